// Round 13
// baseline (571.080 us; speedup 1.0000x reference)
//
#include <hip/hip_runtime.h>

#define S_ 256
#define N_ 384
#define C_ 512
#define H_ 8
#define R_ (N_*S_)
#define SPLITK 32
#define NPK (N_/SPLITK)   // 12

typedef _Float16 f16;
typedef _Float16 f16x8 __attribute__((ext_vector_type(8)));
typedef float f32x4 __attribute__((ext_vector_type(4)));

#define MFMA16(a,b,c) __builtin_amdgcn_mfma_f32_16x16x32_f16(a,b,c,0,0,0)

typedef __attribute__((address_space(3))) unsigned int as3_u32;
typedef __attribute__((address_space(1))) const unsigned int as1_u32;

// async global->LDS, 16B per lane; l must be the wave-uniform base
__device__ __forceinline__ void gl_lds16(const void* g, void* l) {
    __builtin_amdgcn_global_load_lds((as1_u32*)(unsigned long long)g,
                                     (as3_u32*)(unsigned long long)l, 16, 0, 0);
}

// [row][64] f16 tile; granule (8 f16 = 16B) XOR-swizzled with row&7
__device__ __forceinline__ int swz_off(int row, int g) {
    return row*64 + (((g) ^ (row & 7)) << 3);
}

// ---- 512-thread staging of a [128][64] f16 tile pair; linear LDS dest,
// inverse-swizzled global source (rule #21). 4 gl_lds per thread. ----
__device__ __forceinline__ void stage8(const f16* __restrict__ Ab,
                                       const f16* __restrict__ Bb,
                                       int stride, f16* As_, f16* Bs_,
                                       int tid, int wid) {
#pragma unroll
    for (int i = 0; i < 2; ++i) {
        int id = (i << 9) + tid;
        int row = id >> 3, g = (id & 7) ^ (row & 7);
        int lofs = ((i << 9) + (wid << 6)) << 4;   // wave-uniform LDS byte base
        gl_lds16(Ab + row * stride + (g << 3), (char*)As_ + lofs);
        gl_lds16(Bb + row * stride + (g << 3), (char*)Bs_ + lofs);
    }
}

// ---- K=64 MFMA step, 8-wave split: wave owns 64x32 (acc[4][2]) ----
__device__ __forceinline__ void mma8(const f16* As_, const f16* Bs_,
                                     int lane, int wr, int wc, f32x4 acc[4][2]) {
#pragma unroll
    for (int ks = 0; ks < 64; ks += 32) {
        int kg = (ks >> 3) + (lane >> 4);
        f16x8 af[4], bf[2];
#pragma unroll
        for (int m = 0; m < 4; ++m)
            af[m] = *(const f16x8*)&As_[swz_off(wr + (m << 4) + (lane & 15), kg)];
#pragma unroll
        for (int j = 0; j < 2; ++j)
            bf[j] = *(const f16x8*)&Bs_[swz_off(wc + (j << 4) + (lane & 15), kg)];
#pragma unroll
        for (int m = 0; m < 4; ++m)
#pragma unroll
            for (int j = 0; j < 2; ++j)
                acc[m][j] = MFMA16(af[m], bf[j], acc[m][j]);
    }
}

// ---- BK=32 variants (bisect: used ONLY in k_logits this round) ----
__device__ __forceinline__ void stage32q(const f16* __restrict__ Ab,
                                         const f16* __restrict__ Bb,
                                         int stride, f16* As_, f16* Bs_,
                                         int tid, int wid) {
    int row = tid >> 2, g = (tid & 3) ^ ((row >> 1) & 3);
    int lofs = (wid << 6) << 4;                  // wave-uniform LDS byte base
    gl_lds16(Ab + row * stride + (g << 3), (char*)As_ + lofs);
    gl_lds16(Bb + row * stride + (g << 3), (char*)Bs_ + lofs);
}

__device__ __forceinline__ void mma32w8(const f16* As_, const f16* Bs_,
                                        int lane, int wr, int wc, f32x4 acc[4][2]) {
    int kg = lane >> 4;
    f16x8 af[4], bf[2];
#pragma unroll
    for (int m = 0; m < 4; ++m) {
        int row = wr + (m << 4) + (lane & 15);
        af[m] = *(const f16x8*)&As_[row * 32 + ((kg ^ ((row >> 1) & 3)) << 3)];
    }
#pragma unroll
    for (int j = 0; j < 2; ++j) {
        int row = wc + (j << 4) + (lane & 15);
        bf[j] = *(const f16x8*)&Bs_[row * 32 + ((kg ^ ((row >> 1) & 3)) << 3)];
    }
#pragma unroll
    for (int m = 0; m < 4; ++m)
#pragma unroll
        for (int j = 0; j < 2; ++j)
            acc[m][j] = MFMA16(af[m], bf[j], acc[m][j]);
}

// fused weight-cast + msa transpose-cast
// msaT[r=(n*256+s)][c] = (f16)msa[s][n][c]
__global__ __launch_bounds__(256) void k_cast(const float* __restrict__ msa,
                                              const float* __restrict__ Wqkv,
                                              const float* __restrict__ Wout,
                                              f16* __restrict__ msaT,
                                              f16* __restrict__ Wq16,
                                              f16* __restrict__ Wo16) {
    int t = blockIdx.x * 256 + threadIdx.x;
    if (t < 1536 * C_) Wq16[t] = (f16)Wqkv[t];
    if (t < C_ * C_)   Wo16[t] = (f16)Wout[t];
    int r = t >> 6, cg = t & 63;
    int n = r >> 8, s = r & 255;
    const float* src = msa + (s * N_ + n) * C_ + (cg << 3);
    float4 lo = *(const float4*)src;
    float4 hi = *(const float4*)(src + 4);
    f16x8 v;
    v[0]=(f16)lo.x; v[1]=(f16)lo.y; v[2]=(f16)lo.z; v[3]=(f16)lo.w;
    v[4]=(f16)hi.x; v[5]=(f16)hi.y; v[6]=(f16)hi.z; v[7]=(f16)hi.w;
    *(f16x8*)(msaT + r * C_ + (cg << 3)) = v;
}

// qh[h][r][64], kh[h][r][64], vT[n][h][d][t] from msaT @ Wqkv^T + bqkv
// 8 waves, BK=64, double-buffered, counted-vmcnt pipeline (R8/R10/R11-proven).
__global__ __launch_bounds__(512) void k_qkv(const f16* __restrict__ msaT,
                                             const f16* __restrict__ W,
                                             const float* __restrict__ bqkv,
                                             f16* __restrict__ qh,
                                             f16* __restrict__ kh,
                                             f16* __restrict__ vT) {
    int wg = (blockIdx.x & 7) * 1152 + (blockIdx.x >> 3);   // 9216 = 8*1152 exact
    int bx = wg / 12, by = wg % 12;
    int j0 = by << 7;
    int tid = threadIdx.x, lane = tid & 63, wid = tid >> 6;
    int wr = (wid >> 2) << 6, wc = (wid & 3) << 5;
    __shared__ f16 SH[32768];   // As0@0, Bs0@8192, As1@16384, Bs1@24576 (f16 units)
    const f16* Abase = msaT + (bx << 7) * C_;
    const f16* Bbase = W + j0 * C_;
    f32x4 acc[4][2] = {};
    stage8(Abase, Bbase, C_, SH, SH + 8192, tid, wid);
    for (int kt = 0; kt < 8; ++kt) {
        int cur = kt & 1;
        if (kt < 7) {
            stage8(Abase + ((kt + 1) << 6), Bbase + ((kt + 1) << 6), C_,
                   SH + ((cur ^ 1) << 14), SH + 8192 + ((cur ^ 1) << 14), tid, wid);
            asm volatile("s_waitcnt vmcnt(4)" ::: "memory");
        } else {
            asm volatile("s_waitcnt vmcnt(0)" ::: "memory");
        }
        asm volatile("s_barrier" ::: "memory");
        mma8(SH + (cur << 14), SH + 8192 + (cur << 14), lane, wr, wc, acc);
        asm volatile("s_barrier" ::: "memory");
    }
    // ---- epilogue: [128][140] stage (conflict-free strides), coalesced stores ----
    if (by < 8) {
#pragma unroll
        for (int m = 0; m < 4; ++m) {
            int rl = wr + (m << 4) + ((lane >> 4) << 2);
#pragma unroll
            for (int j = 0; j < 2; ++j) {
                int col = wc + (j << 4) + (lane & 15);
                float bv = bqkv[j0 + col];
#pragma unroll
                for (int q = 0; q < 4; ++q)
                    SH[(rl + q) * 140 + col] = (f16)(acc[m][j][q] + bv);
            }
        }
        __syncthreads();
        f16* dst = (by < 4) ? qh : kh;
        int jb0 = j0 & 511;
#pragma unroll
        for (int i = 0; i < 4; ++i) {
            int u = (i << 9) + tid;
            int row = u >> 4, seg = u & 15;
            int jh = jb0 + (seg << 3);
            int hh = jh >> 6, d = jh & 63;
            *(f16x8*)(dst + (hh * R_ + (bx << 7) + row) * 64 + d) =
                *(const f16x8*)&SH[row * 140 + (seg << 3)];
        }
    } else {
        int n = bx >> 1, t0g = (bx & 1) << 7;
#pragma unroll
        for (int m = 0; m < 4; ++m) {
            int rl = wr + (m << 4) + ((lane >> 4) << 2);
#pragma unroll
            for (int j = 0; j < 2; ++j) {
                int col = wc + (j << 4) + (lane & 15);
                float bv = bqkv[1024 + ((by - 8) << 7) + col];
#pragma unroll
                for (int q = 0; q < 4; ++q)
                    SH[col * 140 + rl + q] = (f16)(acc[m][j][q] + bv);   // transpose
            }
        }
        __syncthreads();
#pragma unroll
        for (int i = 0; i < 4; ++i) {
            int u = (i << 9) + tid;
            int lcol = u >> 4, seg = u & 15;
            int jg = ((by - 8) << 7) + lcol;
            *(f16x8*)(vT + ((n * H_ + (jg >> 6)) * 64 + (jg & 63)) * S_ + t0g + (seg << 3)) =
                *(const f16x8*)&SH[lcol * 140 + (seg << 3)];
        }
    }
}

// partial logits: logP[sk][h][s][t] = sum_{n in chunk, d} q[n,s,h,d]*k[n,t,h,d]
// BISECT: BK=32 variant (24 iters of (n, d-half)), counted vmcnt(2);
// 32 KB LDS -> 4 blocks/CU (100% occupancy), 1024 blocks = one residency round.
__global__ __launch_bounds__(512) void k_logits(const f16* __restrict__ qh,
                                                const f16* __restrict__ kh,
                                                float* __restrict__ logP) {
    int wg = (blockIdx.x & 7) * 128 + (blockIdx.x >> 3);    // 1024 = 8*128 exact
    int sk = wg >> 5, rem = wg & 31, h = rem >> 2, sb = (rem >> 1) & 1, tb = rem & 1;
    int s0 = sb << 7, t0 = tb << 7, n0 = sk * NPK;
    int tid = threadIdx.x, lane = tid & 63, wid = tid >> 6;
    int wr = (wid >> 2) << 6, wc = (wid & 3) << 5;
    __shared__ f16 SH[16384];   // buf b at b*8192: As[128][32]@+0, Bs[128][32]@+4096
    const f16* Aroot = qh + (h * R_ + s0) * 64;
    const f16* Broot = kh + (h * R_ + t0) * 64;
    f32x4 acc[4][2] = {};
    stage32q(Aroot + n0 * S_ * 64, Broot + n0 * S_ * 64, 64, SH, SH + 4096, tid, wid);
    for (int t = 0; t < 2 * NPK; ++t) {
        int cur = t & 1;
        if (t < 2 * NPK - 1) {
            int tn = t + 1;
            int n = n0 + (tn >> 1), dh = (tn & 1) << 5;
            stage32q(Aroot + n * S_ * 64 + dh, Broot + n * S_ * 64 + dh, 64,
                     SH + ((cur ^ 1) << 13), SH + 4096 + ((cur ^ 1) << 13), tid, wid);
            asm volatile("s_waitcnt vmcnt(2)" ::: "memory");
        } else {
            asm volatile("s_waitcnt vmcnt(0)" ::: "memory");
        }
        asm volatile("s_barrier" ::: "memory");
        mma32w8(SH + (cur << 13), SH + 4096 + (cur << 13), lane, wr, wc, acc);
        asm volatile("s_barrier" ::: "memory");
    }
#pragma unroll
    for (int m = 0; m < 4; ++m) {
        int rl = wr + (m << 4) + ((lane >> 4) << 2);
#pragma unroll
        for (int j = 0; j < 2; ++j) {
            int tc = t0 + wc + (j << 4) + (lane & 15);
#pragma unroll
            for (int q = 0; q < 4; ++q)
                logP[((sk * H_ + h) * S_ + s0 + rl + q) * S_ + tc] = acc[m][j][q];
        }
    }
}

__global__ __launch_bounds__(256) void k_softmax(const float* __restrict__ logP,
                                                 const int* __restrict__ mask,
                                                 f16* __restrict__ attn) {
    int hs = blockIdx.x;  // h*256 + s
    int t = threadIdx.x, lane = t & 63, wid = t >> 6;
    float v = 0.f;
#pragma unroll
    for (int sk = 0; sk < SPLITK; ++sk)
        v += logP[(sk * H_ * S_ + hs) * S_ + t];
    v *= 0.125f;
    if (mask[t] == 0) v = -1e9f;
    __shared__ float redm[4], reds[4];
    float m_ = v;
    for (int o = 32; o > 0; o >>= 1) m_ = fmaxf(m_, __shfl_xor(m_, o));
    if (lane == 0) redm[wid] = m_;
    __syncthreads();
    float bm = fmaxf(fmaxf(redm[0], redm[1]), fmaxf(redm[2], redm[3]));
    float e = __expf(v - bm);
    float s_ = e;
    for (int o = 32; o > 0; o >>= 1) s_ += __shfl_xor(s_, o);
    if (lane == 0) reds[wid] = s_;
    __syncthreads();
    float tot = reds[0] + reds[1] + reds[2] + reds[3];
    attn[hs * S_ + t] = (f16)(e / tot);
}

// ---- k_pv staging: As[256][32]@buf, Bs[64][32]@buf+8192 (f16 units) ----
__device__ __forceinline__ void stage_pv(const f16* __restrict__ Ab,
                                         const f16* __restrict__ Bb,
                                         int c0, f16* buf, int tid, int wid) {
#pragma unroll
    for (int i = 0; i < 4; ++i) {                 // As: 256 rows x 32
        int id = (i << 8) + tid;
        int row = id >> 2, g = (id & 3) ^ ((row >> 1) & 3);
        gl_lds16(Ab + row * S_ + c0 + (g << 3),
                 (char*)buf + (((i << 8) + (wid << 6)) << 4));
    }
    {                                             // Bs: 64 rows x 32
        int row = tid >> 2, g = (tid & 3) ^ ((row >> 1) & 3);
        gl_lds16(Bb + row * S_ + c0 + (g << 3),
                 (char*)(buf + 8192) + ((wid << 6) << 4));
    }
}

// attn_out[n][s][h*64+d] = sum_t attn[h][s][t] * vT[n][h][d][t]
// BK=32 double-buffered, syncthreads-fenced (R4/R11-proven template).
__global__ __launch_bounds__(256) void k_pv(const f16* __restrict__ attn,
                                            const f16* __restrict__ vT,
                                            f16* __restrict__ attn_out) {
    int n = blockIdx.x >> 3, h = blockIdx.x & 7;
    int tid = threadIdx.x, lane = tid & 63, wid = tid >> 6;
    __shared__ f16 SH[20480];   // buf b at b*10240: As[256][32]@+0, Bs[64][32]@+8192
    f32x4 acc[4][4] = {};
    const f16* Ab = attn + h * S_ * S_;
    const f16* Bb = vT + (n * H_ + h) * 64 * S_;
    stage_pv(Ab, Bb, 0, SH, tid, wid);
    __syncthreads();
    for (int tt = 0; tt < 8; ++tt) {
        int cur = tt & 1;
        if (tt < 7)
            stage_pv(Ab, Bb, (tt + 1) << 5, SH + (cur ^ 1) * 10240, tid, wid);
        {
            const f16* As_ = SH + cur * 10240;
            const f16* Bs_ = As_ + 8192;
            int kg = lane >> 4;
            f16x8 af[4], bf[4];
#pragma unroll
            for (int m = 0; m < 4; ++m) {
                int row = (wid << 6) + (m << 4) + (lane & 15);
                af[m] = *(const f16x8*)&As_[row * 32 + ((kg ^ ((row >> 1) & 3)) << 3)];
            }
#pragma unroll
            for (int j = 0; j < 4; ++j) {
                int row = (j << 4) + (lane & 15);
                bf[j] = *(const f16x8*)&Bs_[row * 32 + ((kg ^ ((row >> 1) & 3)) << 3)];
            }
#pragma unroll
            for (int m = 0; m < 4; ++m)
#pragma unroll
                for (int j = 0; j < 4; ++j)
                    acc[m][j] = MFMA16(af[m], bf[j], acc[m][j]);
        }
        __syncthreads();
    }
    // epilogue: [128][140] stage halves, coalesced f16x8 stores
#pragma unroll
    for (int p = 0; p < 2; ++p) {
        __syncthreads();
#pragma unroll
        for (int mm = 0; mm < 2; ++mm) {
            int m = 2 * p + mm;
            int rl = ((m & 1) << 4) + ((lane >> 4) << 2);
            int lrow = (wid << 5) + rl;                      // 0..127
#pragma unroll
            for (int j = 0; j < 4; ++j) {
                int d = (j << 4) + (lane & 15);
#pragma unroll
                for (int q = 0; q < 4; ++q)
                    SH[(lrow + q) * 140 + d] = (f16)acc[m][j][q];
            }
        }
        __syncthreads();
#pragma unroll
        for (int i = 0; i < 4; ++i) {
            int u = tid + (i << 8);
            int row = u >> 3, seg = u & 7;
            int s = ((row >> 5) << 6) + (p << 5) + (row & 31);
            *(f16x8*)(attn_out + (n * S_ + s) * C_ + (h << 6) + (seg << 3)) =
                *(const f16x8*)&SH[row * 140 + (seg << 3)];
        }
    }
}

// ---- k_out_ln staging: As[64][32]@buf, Bs[512][32]@buf+2048 (f16 units) ----
__device__ __forceinline__ void stage_ol(const f16* __restrict__ attn_out,
                                         const f16* __restrict__ Wo,
                                         int r0, int c0, f16* buf, int tid, int wid) {
    if (tid < 256) {                              // As: 64 rows x 32 (waves 0-3)
        int row = tid >> 2, g = (tid & 3) ^ ((row >> 1) & 3);
        gl_lds16(attn_out + (r0 + row) * C_ + c0 + (g << 3),
                 (char*)buf + ((wid << 6) << 4));
    }
#pragma unroll
    for (int i = 0; i < 4; ++i) {                 // Bs: 512 rows x 32
        int id = (i << 9) + tid;
        int row = id >> 2, g = (id & 3) ^ ((row >> 1) & 3);
        gl_lds16(Wo + row * C_ + c0 + (g << 3),
                 (char*)(buf + 2048) + (((i << 9) + (wid << 6)) << 4));
    }
}

// y = attn_out @ Wout^T + bout; x = msaT + y; LayerNorm(x) -> out[s][n][c]
// BK=32 double-buffered, syncthreads-fenced (R4/R11-proven template).
__global__ __launch_bounds__(512) void k_out_ln(const f16* __restrict__ attn_out,
                                                const f16* __restrict__ Wo,
                                                const float* __restrict__ bout,
                                                const f16* __restrict__ msaT,
                                                const float* __restrict__ gamma,
                                                const float* __restrict__ beta,
                                                float* __restrict__ out) {
    int r0 = blockIdx.x << 6;
    int n = r0 >> 8, s0 = r0 & 255;
    int tid = threadIdx.x, lane = tid & 63, wid = tid >> 6;
    __shared__ f16 SH[36864];   // buf b at b*18432: As[64][32]@+0, Bs[512][32]@+2048
    __shared__ float redS[8][64], redQ[8][64], muS[64], rsS[64];
    f32x4 acc[4][4] = {};
    stage_ol(attn_out, Wo, r0, 0, SH, tid, wid);
    __syncthreads();
    for (int kt = 0; kt < 16; ++kt) {
        int cur = kt & 1;
        if (kt < 15)
            stage_ol(attn_out, Wo, r0, (kt + 1) << 5, SH + (cur ^ 1) * 18432, tid, wid);
        {
            const f16* As_ = SH + cur * 18432;
            const f16* Bs_ = As_ + 2048;
            int kg = lane >> 4;
            f16x8 af[4], bf[4];
#pragma unroll
            for (int m = 0; m < 4; ++m) {
                int row = (m << 4) + (lane & 15);
                af[m] = *(const f16x8*)&As_[row * 32 + ((kg ^ ((row >> 1) & 3)) << 3)];
            }
#pragma unroll
            for (int j = 0; j < 4; ++j) {
                int row = (wid << 6) + (j << 4) + (lane & 15);
                bf[j] = *(const f16x8*)&Bs_[row * 32 + ((kg ^ ((row >> 1) & 3)) << 3)];
            }
#pragma unroll
            for (int m = 0; m < 4; ++m)
#pragma unroll
                for (int j = 0; j < 4; ++j)
                    acc[m][j] = MFMA16(af[m], bf[j], acc[m][j]);
        }
        __syncthreads();
    }
    float psum[4][4] = {}, psq[4][4] = {};
#pragma unroll
    for (int m = 0; m < 4; ++m)
#pragma unroll
        for (int j = 0; j < 4; ++j) {
            int c = (wid << 6) + (j << 4) + (lane & 15);
            float bj = bout[c];
#pragma unroll
            for (int q = 0; q < 4; ++q) {
                int rl = (m << 4) + ((lane >> 4) << 2) + q;
                float x = acc[m][j][q] + bj + (float)msaT[(r0 + rl) * C_ + c];
                acc[m][j][q] = x;
                psum[m][q] += x;
                psq[m][q] += x * x;
            }
        }
#pragma unroll
    for (int m = 0; m < 4; ++m)
#pragma unroll
        for (int q = 0; q < 4; ++q)
            for (int o = 1; o < 16; o <<= 1) {
                psum[m][q] += __shfl_xor(psum[m][q], o);
                psq[m][q]  += __shfl_xor(psq[m][q], o);
            }
    if ((lane & 15) == 0) {
#pragma unroll
        for (int m = 0; m < 4; ++m)
#pragma unroll
            for (int q = 0; q < 4; ++q) {
                int rl = (m << 4) + ((lane >> 4) << 2) + q;
                redS[wid][rl] = psum[m][q];
                redQ[wid][rl] = psq[m][q];
            }
    }
    __syncthreads();
    if (tid < 64) {
        float t1 = 0.f, t2 = 0.f;
#pragma unroll
        for (int w = 0; w < 8; ++w) { t1 += redS[w][tid]; t2 += redQ[w][tid]; }
        float mu = t1 * (1.0f / 512.0f);
        float var = t2 * (1.0f / 512.0f) - mu * mu;
        muS[tid] = mu;
        rsS[tid] = rsqrtf(var + 1e-5f);
    }
    __syncthreads();
#pragma unroll
    for (int m = 0; m < 4; ++m)
#pragma unroll
        for (int j = 0; j < 4; ++j) {
            int c = (wid << 6) + (j << 4) + (lane & 15);
            float g = gamma[c], bb = beta[c];
#pragma unroll
            for (int q = 0; q < 4; ++q) {
                int rl = (m << 4) + ((lane >> 4) << 2) + q;
                int s = s0 + rl;
                float y = (acc[m][j][q] - muS[rl]) * rsS[rl] * g + bb;
                out[(s * N_ + n) * C_ + c] = y;
            }
        }
}

extern "C" void kernel_launch(void* const* d_in, const int* in_sizes, int n_in,
                              void* d_out, int out_size, void* d_ws, size_t ws_size,
                              hipStream_t stream) {
    const float* msa   = (const float*)d_in[0];
    const int*   mask  = (const int*)d_in[1];
    const float* Wqkv  = (const float*)d_in[2];
    const float* bqkv  = (const float*)d_in[3];
    const float* Wout  = (const float*)d_in[4];
    const float* bout  = (const float*)d_in[5];
    const float* gamma = (const float*)d_in[6];
    const float* beta  = (const float*)d_in[7];
    float* out = (float*)d_out;
    char* ws = (char*)d_ws;

    f16*   qh   = (f16*)(ws);                        // 100,663,296 B  [h][r][64]
    f16*   kh   = (f16*)(ws + 100663296);            // 100,663,296 B  [h][r][64]
    f16*   vT   = (f16*)(ws + 201326592);            // 100,663,296 B  [n][h][d][t]
    f16*   msaT = (f16*)(ws + 301989888);            // 100,663,296 B
    f16*   attn = (f16*)(ws + 402653184);            //   1,048,576 B
    f16*   Wq16 = (f16*)(ws + 403701760);            //   1,572,864 B
    f16*   Wo16 = (f16*)(ws + 405274624);            //     524,288 B
    float* logP = out;                               // d_out as scratch (67 MB of 201 MB);
                                                     // k_out_ln overwrites d_out last
    f16*   attn_out = qh;                            // alias: q/k dead after k_logits

    k_cast<<<dim3(24576), dim3(256), 0, stream>>>(msa, Wqkv, Wout, msaT, Wq16, Wo16);
    k_qkv<<<dim3(9216), dim3(512), 0, stream>>>(msaT, Wq16, bqkv, qh, kh, vT);
    k_logits<<<dim3(1024), dim3(512), 0, stream>>>(qh, kh, logP);
    k_softmax<<<dim3(2048), dim3(256), 0, stream>>>(logP, mask, attn);
    k_pv<<<dim3(3072), dim3(256), 0, stream>>>(attn, vT, attn_out);
    k_out_ln<<<dim3(1536), dim3(512), 0, stream>>>(attn_out, Wo16, bout, msaT, gamma, beta, out);
}

// Round 14
// 560.690 us; speedup vs baseline: 1.0185x; 1.0185x over previous
//
#include <hip/hip_runtime.h>

#define S_ 256
#define N_ 384
#define C_ 512
#define H_ 8
#define R_ (N_*S_)
#define SPLITK 32
#define NPK (N_/SPLITK)   // 12

typedef _Float16 f16;
typedef _Float16 f16x8 __attribute__((ext_vector_type(8)));
typedef float f32x4 __attribute__((ext_vector_type(4)));

#define MFMA16(a,b,c) __builtin_amdgcn_mfma_f32_16x16x32_f16(a,b,c,0,0,0)

typedef __attribute__((address_space(3))) unsigned int as3_u32;
typedef __attribute__((address_space(1))) const unsigned int as1_u32;

// async global->LDS, 16B per lane; l must be the wave-uniform base
__device__ __forceinline__ void gl_lds16(const void* g, void* l) {
    __builtin_amdgcn_global_load_lds((as1_u32*)(unsigned long long)g,
                                     (as3_u32*)(unsigned long long)l, 16, 0, 0);
}

// [row][64] f16 tile; granule (8 f16 = 16B) XOR-swizzled with row&7
__device__ __forceinline__ int swz_off(int row, int g) {
    return row*64 + (((g) ^ (row & 7)) << 3);
}

// ---- stage one [128][64] f16 tile (row-stride 512) with 512 threads;
// linear LDS dest, inverse-swizzled global source (rule #21). 2 gl_lds/thread.
__device__ __forceinline__ void stage2(const f16* __restrict__ Tb, f16* Ts_,
                                       int tid, int wid) {
#pragma unroll
    for (int i = 0; i < 2; ++i) {
        int id = (i << 9) + tid;
        int row = id >> 3, g = (id & 7) ^ (row & 7);
        gl_lds16(Tb + row * C_ + (g << 3),
                 (char*)Ts_ + (((i << 9) + (wid << 6)) << 4));
    }
}

// ---- K=64 MFMA step, 8-wave split: wave owns 64x32 (acc[4][2]) ----
__device__ __forceinline__ void mma8(const f16* As_, const f16* Bs_,
                                     int lane, int wr, int wc, f32x4 acc[4][2]) {
#pragma unroll
    for (int ks = 0; ks < 64; ks += 32) {
        int kg = (ks >> 3) + (lane >> 4);
        f16x8 af[4], bf[2];
#pragma unroll
        for (int m = 0; m < 4; ++m)
            af[m] = *(const f16x8*)&As_[swz_off(wr + (m << 4) + (lane & 15), kg)];
#pragma unroll
        for (int j = 0; j < 2; ++j)
            bf[j] = *(const f16x8*)&Bs_[swz_off(wc + (j << 4) + (lane & 15), kg)];
#pragma unroll
        for (int m = 0; m < 4; ++m)
#pragma unroll
            for (int j = 0; j < 2; ++j)
                acc[m][j] = MFMA16(af[m], bf[j], acc[m][j]);
    }
}

// ---- BK=32 helpers (k_logits; R13-proven) ----
__device__ __forceinline__ void stage32q(const f16* __restrict__ Ab,
                                         const f16* __restrict__ Bb,
                                         int stride, f16* As_, f16* Bs_,
                                         int tid, int wid) {
    int row = tid >> 2, g = (tid & 3) ^ ((row >> 1) & 3);
    int lofs = (wid << 6) << 4;                  // wave-uniform LDS byte base
    gl_lds16(Ab + row * stride + (g << 3), (char*)As_ + lofs);
    gl_lds16(Bb + row * stride + (g << 3), (char*)Bs_ + lofs);
}

__device__ __forceinline__ void mma32w8(const f16* As_, const f16* Bs_,
                                        int lane, int wr, int wc, f32x4 acc[4][2]) {
    int kg = lane >> 4;
    f16x8 af[4], bf[2];
#pragma unroll
    for (int m = 0; m < 4; ++m) {
        int row = wr + (m << 4) + (lane & 15);
        af[m] = *(const f16x8*)&As_[row * 32 + ((kg ^ ((row >> 1) & 3)) << 3)];
    }
#pragma unroll
    for (int j = 0; j < 2; ++j) {
        int row = wc + (j << 4) + (lane & 15);
        bf[j] = *(const f16x8*)&Bs_[row * 32 + ((kg ^ ((row >> 1) & 3)) << 3)];
    }
#pragma unroll
    for (int m = 0; m < 4; ++m)
#pragma unroll
        for (int j = 0; j < 2; ++j)
            acc[m][j] = MFMA16(af[m], bf[j], acc[m][j]);
}

// fused weight-cast + msa transpose-cast
// msaT[r=(n*256+s)][c] = (f16)msa[s][n][c]
__global__ __launch_bounds__(256) void k_cast(const float* __restrict__ msa,
                                              const float* __restrict__ Wqkv,
                                              const float* __restrict__ Wout,
                                              f16* __restrict__ msaT,
                                              f16* __restrict__ Wq16,
                                              f16* __restrict__ Wo16) {
    int t = blockIdx.x * 256 + threadIdx.x;
    if (t < 1536 * C_) Wq16[t] = (f16)Wqkv[t];
    if (t < C_ * C_)   Wo16[t] = (f16)Wout[t];
    int r = t >> 6, cg = t & 63;
    int n = r >> 8, s = r & 255;
    const float* src = msa + (s * N_ + n) * C_ + (cg << 3);
    float4 lo = *(const float4*)src;
    float4 hi = *(const float4*)(src + 4);
    f16x8 v;
    v[0]=(f16)lo.x; v[1]=(f16)lo.y; v[2]=(f16)lo.z; v[3]=(f16)lo.w;
    v[4]=(f16)hi.x; v[5]=(f16)hi.y; v[6]=(f16)hi.z; v[7]=(f16)hi.w;
    *(f16x8*)(msaT + r * C_ + (cg << 3)) = v;
}

// qh[h][r][64], kh[h][r][64], vT[n][h][d][t] from msaT @ Wqkv^T + bqkv
// 8 waves, BK=64, 2-deep pipeline: 3 A-slots + 2 B-slots (80 KB LDS,
// 2 blocks/CU), counted vmcnt {6,4,0}. Stage/mma/swizzle/epilogue are
// byte-identical to the R8/R13-proven k_qkv; only slot rotation + counts new.
__global__ __launch_bounds__(512) void k_qkv(const f16* __restrict__ msaT,
                                             const f16* __restrict__ W,
                                             const float* __restrict__ bqkv,
                                             f16* __restrict__ qh,
                                             f16* __restrict__ kh,
                                             f16* __restrict__ vT) {
    int wg = (blockIdx.x & 7) * 1152 + (blockIdx.x >> 3);   // 9216 = 8*1152 exact
    int bx = wg / 12, by = wg % 12;
    int j0 = by << 7;
    int tid = threadIdx.x, lane = tid & 63, wid = tid >> 6;
    int wr = (wid >> 2) << 6, wc = (wid & 3) << 5;
    __shared__ f16 SH[40960];   // A slots a=0..2 @ a*8192; B slots b=0..1 @ 24576+b*8192
    const f16* Abase = msaT + (bx << 7) * C_;
    const f16* Bbase = W + j0 * C_;
    f32x4 acc[4][2] = {};
    // prologue (FIFO: A0 < B0 < A1)
    stage2(Abase,      SH,         tid, wid);            // A step0 -> slot0
    stage2(Bbase,      SH + 24576, tid, wid);            // B step0 -> slot0
    stage2(Abase + 64, SH + 8192,  tid, wid);            // A step1 -> slot1
#pragma unroll
    for (int kt = 0; kt < 8; ++kt) {
        if (kt + 1 < 8)
            stage2(Bbase + ((kt + 1) << 6), SH + 24576 + ((kt + 1) & 1) * 8192, tid, wid);
        if (kt + 2 < 8)
            stage2(Abase + ((kt + 2) << 6), SH + ((kt + 2) % 3) * 8192, tid, wid);
        // outstanding: A(kt),B(kt),A(kt+1),B(kt+1),A(kt+2) = 10 -> retire oldest 4
        if (kt < 6)       { asm volatile("s_waitcnt vmcnt(6)" ::: "memory"); }
        else if (kt == 6) { asm volatile("s_waitcnt vmcnt(4)" ::: "memory"); }
        else              { asm volatile("s_waitcnt vmcnt(0)" ::: "memory"); }
        asm volatile("s_barrier" ::: "memory");
        mma8(SH + (kt % 3) * 8192, SH + 24576 + (kt & 1) * 8192, lane, wr, wc, acc);
        asm volatile("s_barrier" ::: "memory");
    }
    // ---- epilogue: [128][140] stage (conflict-free strides), coalesced stores ----
    if (by < 8) {
#pragma unroll
        for (int m = 0; m < 4; ++m) {
            int rl = wr + (m << 4) + ((lane >> 4) << 2);
#pragma unroll
            for (int j = 0; j < 2; ++j) {
                int col = wc + (j << 4) + (lane & 15);
                float bv = bqkv[j0 + col];
#pragma unroll
                for (int q = 0; q < 4; ++q)
                    SH[(rl + q) * 140 + col] = (f16)(acc[m][j][q] + bv);
            }
        }
        __syncthreads();
        f16* dst = (by < 4) ? qh : kh;
        int jb0 = j0 & 511;
#pragma unroll
        for (int i = 0; i < 4; ++i) {
            int u = (i << 9) + tid;
            int row = u >> 4, seg = u & 15;
            int jh = jb0 + (seg << 3);
            int hh = jh >> 6, d = jh & 63;
            *(f16x8*)(dst + (hh * R_ + (bx << 7) + row) * 64 + d) =
                *(const f16x8*)&SH[row * 140 + (seg << 3)];
        }
    } else {
        int n = bx >> 1, t0g = (bx & 1) << 7;
#pragma unroll
        for (int m = 0; m < 4; ++m) {
            int rl = wr + (m << 4) + ((lane >> 4) << 2);
#pragma unroll
            for (int j = 0; j < 2; ++j) {
                int col = wc + (j << 4) + (lane & 15);
                float bv = bqkv[1024 + ((by - 8) << 7) + col];
#pragma unroll
                for (int q = 0; q < 4; ++q)
                    SH[col * 140 + rl + q] = (f16)(acc[m][j][q] + bv);   // transpose
            }
        }
        __syncthreads();
#pragma unroll
        for (int i = 0; i < 4; ++i) {
            int u = (i << 9) + tid;
            int lcol = u >> 4, seg = u & 15;
            int jg = ((by - 8) << 7) + lcol;
            *(f16x8*)(vT + ((n * H_ + (jg >> 6)) * 64 + (jg & 63)) * S_ + t0g + (seg << 3)) =
                *(const f16x8*)&SH[lcol * 140 + (seg << 3)];
        }
    }
}

// partial logits: logP[sk][h][s][t] = sum_{n in chunk, d} q[n,s,h,d]*k[n,t,h,d]
// BK=32 (24 iters of (n, d-half)), counted vmcnt(2); R13-proven.
__global__ __launch_bounds__(512) void k_logits(const f16* __restrict__ qh,
                                                const f16* __restrict__ kh,
                                                float* __restrict__ logP) {
    int wg = (blockIdx.x & 7) * 128 + (blockIdx.x >> 3);    // 1024 = 8*128 exact
    int sk = wg >> 5, rem = wg & 31, h = rem >> 2, sb = (rem >> 1) & 1, tb = rem & 1;
    int s0 = sb << 7, t0 = tb << 7, n0 = sk * NPK;
    int tid = threadIdx.x, lane = tid & 63, wid = tid >> 6;
    int wr = (wid >> 2) << 6, wc = (wid & 3) << 5;
    __shared__ f16 SH[16384];   // buf b at b*8192: As[128][32]@+0, Bs[128][32]@+4096
    const f16* Aroot = qh + (h * R_ + s0) * 64;
    const f16* Broot = kh + (h * R_ + t0) * 64;
    f32x4 acc[4][2] = {};
    stage32q(Aroot + n0 * S_ * 64, Broot + n0 * S_ * 64, 64, SH, SH + 4096, tid, wid);
    for (int t = 0; t < 2 * NPK; ++t) {
        int cur = t & 1;
        if (t < 2 * NPK - 1) {
            int tn = t + 1;
            int n = n0 + (tn >> 1), dh = (tn & 1) << 5;
            stage32q(Aroot + n * S_ * 64 + dh, Broot + n * S_ * 64 + dh, 64,
                     SH + ((cur ^ 1) << 13), SH + 4096 + ((cur ^ 1) << 13), tid, wid);
            asm volatile("s_waitcnt vmcnt(2)" ::: "memory");
        } else {
            asm volatile("s_waitcnt vmcnt(0)" ::: "memory");
        }
        asm volatile("s_barrier" ::: "memory");
        mma32w8(SH + (cur << 13), SH + 4096 + (cur << 13), lane, wr, wc, acc);
        asm volatile("s_barrier" ::: "memory");
    }
#pragma unroll
    for (int m = 0; m < 4; ++m) {
        int rl = wr + (m << 4) + ((lane >> 4) << 2);
#pragma unroll
        for (int j = 0; j < 2; ++j) {
            int tc = t0 + wc + (j << 4) + (lane & 15);
#pragma unroll
            for (int q = 0; q < 4; ++q)
                logP[((sk * H_ + h) * S_ + s0 + rl + q) * S_ + tc] = acc[m][j][q];
        }
    }
}

__global__ __launch_bounds__(256) void k_softmax(const float* __restrict__ logP,
                                                 const int* __restrict__ mask,
                                                 f16* __restrict__ attn) {
    int hs = blockIdx.x;  // h*256 + s
    int t = threadIdx.x, lane = t & 63, wid = t >> 6;
    float v = 0.f;
#pragma unroll
    for (int sk = 0; sk < SPLITK; ++sk)
        v += logP[(sk * H_ * S_ + hs) * S_ + t];
    v *= 0.125f;
    if (mask[t] == 0) v = -1e9f;
    __shared__ float redm[4], reds[4];
    float m_ = v;
    for (int o = 32; o > 0; o >>= 1) m_ = fmaxf(m_, __shfl_xor(m_, o));
    if (lane == 0) redm[wid] = m_;
    __syncthreads();
    float bm = fmaxf(fmaxf(redm[0], redm[1]), fmaxf(redm[2], redm[3]));
    float e = __expf(v - bm);
    float s_ = e;
    for (int o = 32; o > 0; o >>= 1) s_ += __shfl_xor(s_, o);
    if (lane == 0) reds[wid] = s_;
    __syncthreads();
    float tot = reds[0] + reds[1] + reds[2] + reds[3];
    attn[hs * S_ + t] = (f16)(e / tot);
}

// ---- k_pv staging: As[256][32]@buf, Bs[64][32]@buf+8192 (f16 units) ----
__device__ __forceinline__ void stage_pv(const f16* __restrict__ Ab,
                                         const f16* __restrict__ Bb,
                                         int c0, f16* buf, int tid, int wid) {
#pragma unroll
    for (int i = 0; i < 4; ++i) {                 // As: 256 rows x 32
        int id = (i << 8) + tid;
        int row = id >> 2, g = (id & 3) ^ ((row >> 1) & 3);
        gl_lds16(Ab + row * S_ + c0 + (g << 3),
                 (char*)buf + (((i << 8) + (wid << 6)) << 4));
    }
    {                                             // Bs: 64 rows x 32
        int row = tid >> 2, g = (tid & 3) ^ ((row >> 1) & 3);
        gl_lds16(Bb + row * S_ + c0 + (g << 3),
                 (char*)(buf + 8192) + ((wid << 6) << 4));
    }
}

// attn_out[n][s][h*64+d] = sum_t attn[h][s][t] * vT[n][h][d][t]
// BK=32 double-buffered, syncthreads-fenced (R4/R11-proven template).
__global__ __launch_bounds__(256) void k_pv(const f16* __restrict__ attn,
                                            const f16* __restrict__ vT,
                                            f16* __restrict__ attn_out) {
    int n = blockIdx.x >> 3, h = blockIdx.x & 7;
    int tid = threadIdx.x, lane = tid & 63, wid = tid >> 6;
    __shared__ f16 SH[20480];   // buf b at b*10240: As[256][32]@+0, Bs[64][32]@+8192
    f32x4 acc[4][4] = {};
    const f16* Ab = attn + h * S_ * S_;
    const f16* Bb = vT + (n * H_ + h) * 64 * S_;
    stage_pv(Ab, Bb, 0, SH, tid, wid);
    __syncthreads();
    for (int tt = 0; tt < 8; ++tt) {
        int cur = tt & 1;
        if (tt < 7)
            stage_pv(Ab, Bb, (tt + 1) << 5, SH + (cur ^ 1) * 10240, tid, wid);
        {
            const f16* As_ = SH + cur * 10240;
            const f16* Bs_ = As_ + 8192;
            int kg = lane >> 4;
            f16x8 af[4], bf[4];
#pragma unroll
            for (int m = 0; m < 4; ++m) {
                int row = (wid << 6) + (m << 4) + (lane & 15);
                af[m] = *(const f16x8*)&As_[row * 32 + ((kg ^ ((row >> 1) & 3)) << 3)];
            }
#pragma unroll
            for (int j = 0; j < 4; ++j) {
                int row = (j << 4) + (lane & 15);
                bf[j] = *(const f16x8*)&Bs_[row * 32 + ((kg ^ ((row >> 1) & 3)) << 3)];
            }
#pragma unroll
            for (int m = 0; m < 4; ++m)
#pragma unroll
                for (int j = 0; j < 4; ++j)
                    acc[m][j] = MFMA16(af[m], bf[j], acc[m][j]);
        }
        __syncthreads();
    }
    // epilogue: [128][140] stage halves, coalesced f16x8 stores
#pragma unroll
    for (int p = 0; p < 2; ++p) {
        __syncthreads();
#pragma unroll
        for (int mm = 0; mm < 2; ++mm) {
            int m = 2 * p + mm;
            int rl = ((m & 1) << 4) + ((lane >> 4) << 2);
            int lrow = (wid << 5) + rl;                      // 0..127
#pragma unroll
            for (int j = 0; j < 4; ++j) {
                int d = (j << 4) + (lane & 15);
#pragma unroll
                for (int q = 0; q < 4; ++q)
                    SH[(lrow + q) * 140 + d] = (f16)acc[m][j][q];
            }
        }
        __syncthreads();
#pragma unroll
        for (int i = 0; i < 4; ++i) {
            int u = tid + (i << 8);
            int row = u >> 3, seg = u & 7;
            int s = ((row >> 5) << 6) + (p << 5) + (row & 31);
            *(f16x8*)(attn_out + (n * S_ + s) * C_ + (h << 6) + (seg << 3)) =
                *(const f16x8*)&SH[row * 140 + (seg << 3)];
        }
    }
}

// ---- k_out_ln staging: As[64][32]@buf, Bs[512][32]@buf+2048 (f16 units) ----
__device__ __forceinline__ void stage_ol(const f16* __restrict__ attn_out,
                                         const f16* __restrict__ Wo,
                                         int r0, int c0, f16* buf, int tid, int wid) {
    if (tid < 256) {                              // As: 64 rows x 32 (waves 0-3)
        int row = tid >> 2, g = (tid & 3) ^ ((row >> 1) & 3);
        gl_lds16(attn_out + (r0 + row) * C_ + c0 + (g << 3),
                 (char*)buf + ((wid << 6) << 4));
    }
#pragma unroll
    for (int i = 0; i < 4; ++i) {                 // Bs: 512 rows x 32
        int id = (i << 9) + tid;
        int row = id >> 2, g = (id & 3) ^ ((row >> 1) & 3);
        gl_lds16(Wo + row * C_ + c0 + (g << 3),
                 (char*)(buf + 2048) + (((i << 9) + (wid << 6)) << 4));
    }
}

// y = attn_out @ Wout^T + bout; x = msaT + y; LayerNorm(x) -> out[s][n][c]
// BK=32 double-buffered, syncthreads-fenced (R4/R11-proven template).
__global__ __launch_bounds__(512) void k_out_ln(const f16* __restrict__ attn_out,
                                                const f16* __restrict__ Wo,
                                                const float* __restrict__ bout,
                                                const f16* __restrict__ msaT,
                                                const float* __restrict__ gamma,
                                                const float* __restrict__ beta,
                                                float* __restrict__ out) {
    int r0 = blockIdx.x << 6;
    int n = r0 >> 8, s0 = r0 & 255;
    int tid = threadIdx.x, lane = tid & 63, wid = tid >> 6;
    __shared__ f16 SH[36864];   // buf b at b*18432: As[64][32]@+0, Bs[512][32]@+2048
    __shared__ float redS[8][64], redQ[8][64], muS[64], rsS[64];
    f32x4 acc[4][4] = {};
    stage_ol(attn_out, Wo, r0, 0, SH, tid, wid);
    __syncthreads();
    for (int kt = 0; kt < 16; ++kt) {
        int cur = kt & 1;
        if (kt < 15)
            stage_ol(attn_out, Wo, r0, (kt + 1) << 5, SH + (cur ^ 1) * 18432, tid, wid);
        {
            const f16* As_ = SH + cur * 18432;
            const f16* Bs_ = As_ + 2048;
            int kg = lane >> 4;
            f16x8 af[4], bf[4];
#pragma unroll
            for (int m = 0; m < 4; ++m) {
                int row = (m << 4) + (lane & 15);
                af[m] = *(const f16x8*)&As_[row * 32 + ((kg ^ ((row >> 1) & 3)) << 3)];
            }
#pragma unroll
            for (int j = 0; j < 4; ++j) {
                int row = (wid << 6) + (j << 4) + (lane & 15);
                bf[j] = *(const f16x8*)&Bs_[row * 32 + ((kg ^ ((row >> 1) & 3)) << 3)];
            }
#pragma unroll
            for (int m = 0; m < 4; ++m)
#pragma unroll
                for (int j = 0; j < 4; ++j)
                    acc[m][j] = MFMA16(af[m], bf[j], acc[m][j]);
        }
        __syncthreads();
    }
    float psum[4][4] = {}, psq[4][4] = {};
#pragma unroll
    for (int m = 0; m < 4; ++m)
#pragma unroll
        for (int j = 0; j < 4; ++j) {
            int c = (wid << 6) + (j << 4) + (lane & 15);
            float bj = bout[c];
#pragma unroll
            for (int q = 0; q < 4; ++q) {
                int rl = (m << 4) + ((lane >> 4) << 2) + q;
                float x = acc[m][j][q] + bj + (float)msaT[(r0 + rl) * C_ + c];
                acc[m][j][q] = x;
                psum[m][q] += x;
                psq[m][q] += x * x;
            }
        }
#pragma unroll
    for (int m = 0; m < 4; ++m)
#pragma unroll
        for (int q = 0; q < 4; ++q)
            for (int o = 1; o < 16; o <<= 1) {
                psum[m][q] += __shfl_xor(psum[m][q], o);
                psq[m][q]  += __shfl_xor(psq[m][q], o);
            }
    if ((lane & 15) == 0) {
#pragma unroll
        for (int m = 0; m < 4; ++m)
#pragma unroll
            for (int q = 0; q < 4; ++q) {
                int rl = (m << 4) + ((lane >> 4) << 2) + q;
                redS[wid][rl] = psum[m][q];
                redQ[wid][rl] = psq[m][q];
            }
    }
    __syncthreads();
    if (tid < 64) {
        float t1 = 0.f, t2 = 0.f;
#pragma unroll
        for (int w = 0; w < 8; ++w) { t1 += redS[w][tid]; t2 += redQ[w][tid]; }
        float mu = t1 * (1.0f / 512.0f);
        float var = t2 * (1.0f / 512.0f) - mu * mu;
        muS[tid] = mu;
        rsS[tid] = rsqrtf(var + 1e-5f);
    }
    __syncthreads();
#pragma unroll
    for (int m = 0; m < 4; ++m)
#pragma unroll
        for (int j = 0; j < 4; ++j) {
            int c = (wid << 6) + (j << 4) + (lane & 15);
            float g = gamma[c], bb = beta[c];
#pragma unroll
            for (int q = 0; q < 4; ++q) {
                int rl = (m << 4) + ((lane >> 4) << 2) + q;
                int s = s0 + rl;
                float y = (acc[m][j][q] - muS[rl]) * rsS[rl] * g + bb;
                out[(s * N_ + n) * C_ + c] = y;
            }
        }
}

extern "C" void kernel_launch(void* const* d_in, const int* in_sizes, int n_in,
                              void* d_out, int out_size, void* d_ws, size_t ws_size,
                              hipStream_t stream) {
    const float* msa   = (const float*)d_in[0];
    const int*   mask  = (const int*)d_in[1];
    const float* Wqkv  = (const float*)d_in[2];
    const float* bqkv  = (const float*)d_in[3];
    const float* Wout  = (const float*)d_in[4];
    const float* bout  = (const float*)d_in[5];
    const float* gamma = (const float*)d_in[6];
    const float* beta  = (const float*)d_in[7];
    float* out = (float*)d_out;
    char* ws = (char*)d_ws;

    f16*   qh   = (f16*)(ws);                        // 100,663,296 B  [h][r][64]
    f16*   kh   = (f16*)(ws + 100663296);            // 100,663,296 B  [h][r][64]
    f16*   vT   = (f16*)(ws + 201326592);            // 100,663,296 B  [n][h][d][t]
    f16*   msaT = (f16*)(ws + 301989888);            // 100,663,296 B
    f16*   attn = (f16*)(ws + 402653184);            //   1,048,576 B
    f16*   Wq16 = (f16*)(ws + 403701760);            //   1,572,864 B
    f16*   Wo16 = (f16*)(ws + 405274624);            //     524,288 B
    float* logP = out;                               // d_out as scratch (67 MB of 201 MB);
                                                     // k_out_ln overwrites d_out last
    f16*   attn_out = qh;                            // alias: q/k dead after k_logits

    k_cast<<<dim3(24576), dim3(256), 0, stream>>>(msa, Wqkv, Wout, msaT, Wq16, Wo16);
    k_qkv<<<dim3(9216), dim3(512), 0, stream>>>(msaT, Wq16, bqkv, qh, kh, vT);
    k_logits<<<dim3(1024), dim3(512), 0, stream>>>(qh, kh, logP);
    k_softmax<<<dim3(2048), dim3(256), 0, stream>>>(logP, mask, attn);
    k_pv<<<dim3(3072), dim3(256), 0, stream>>>(attn, vT, attn_out);
    k_out_ln<<<dim3(1536), dim3(512), 0, stream>>>(attn_out, Wo16, bout, msaT, gamma, beta, out);
}